// Round 8
// baseline (6785.557 us; speedup 1.0000x reference)
//
#include <hip/hip_runtime.h>
#include <math.h>

// QuantumMambaSSMCore R8: R7 + pair-fused Phase C (20 gate rounds -> 10).
//  - 1 wave/block, 128 blocks, 16 amps/thread (v2 = complex).
//  - Storage map: regs r0..r3 = phys {2,4,6,8}; lanes L0..L5 = phys {0,5,1,7,3,9}.
//  - Consecutive SU(2) gates fused on their 4-orbit: out = k00*a + k01*a^V1
//    + k10*a^V2 + k11*a^V12; 4 coeff variants by (p,q) parities, built in
//    prologue into 1.3 KB LDS, fetched per round as 8 lane-indexed b128.
//  - Tables {th, cos, sin} in 74 KB LDS; raw z stored; post-kernel C*z+D*a.

#define PIF 3.14159265358979323846f

constexpr int NQ = 10, SEQ = 512, NB = 128, NTHR = 64, RECF = 36;

struct CTbl { int vu[2][NQ], mu[2][NQ], mz[4][NQ], vf[NQ], zm[NQ], dp[NQ]; };

constexpr CTbl build_tbl() {
  CTbl t{};
  unsigned mrow[NQ], vcol[NQ];
  for (int b = 0; b < NQ; ++b) { mrow[b] = 1u << b; vcol[b] = 1u << b; }
  for (int d = 0; d < 4; ++d) {
    for (int i = 0; i < NQ; ++i) t.mz[d][i] = (int)mrow[9 - i];
    for (int i = 0; i < NQ - 1; ++i) {           // CNOT(i, i+1)
      int bc = 9 - i, bt = 8 - i;
      mrow[bt] ^= mrow[bc];
      vcol[bc] ^= vcol[bt];
    }
    { int bc = 0, bt = 9;                        // CNOT(9, 0)
      mrow[bt] ^= mrow[bc];
      vcol[bc] ^= vcol[bt]; }
  }
  for (int l = 0; l < 2; ++l) {
    for (int i = 0; i < NQ; ++i) { t.vu[l][i] = (int)vcol[9 - i]; t.mu[l][i] = (int)mrow[9 - i]; }
    for (int i = 0; i < NQ - 1; ++i) {
      int bc = 9 - i, bt = 8 - i;
      mrow[bt] ^= mrow[bc];
      vcol[bc] ^= vcol[bt];
    }
  }
  for (int i = 0; i < NQ; ++i) t.vf[i] = (int)vcol[9 - i];
  for (int i = 0; i < NQ; ++i) t.zm[i] = (int)mrow[9 - i];
  // pair constants d = parity(V2 & M1) for fused pairs (2pi, 2pi+1)
  for (int pi = 0; pi < NQ; ++pi) {
    int g1 = 2 * pi, g2 = 2 * pi + 1;
    int V2v = t.vu[g2 / 10][g2 % 10];
    int M1v = t.mu[g1 / 10][g1 % 10];
    int x = V2v & M1v, c = 0;
    for (int b = 0; b < 10; ++b) c ^= (x >> b) & 1;
    t.dp[pi] = c;
  }
  return t;
}
constexpr CTbl CT = build_tbl();

constexpr int regPart(int x)  { return ((x >> 2) & 1) | (((x >> 4) & 1) << 1) |
                                       (((x >> 6) & 1) << 2) | (((x >> 8) & 1) << 3); }
constexpr int lanePart(int x) { return ((x >> 0) & 1) | (((x >> 5) & 1) << 1) |
                                       (((x >> 1) & 1) << 2) | (((x >> 7) & 1) << 3) |
                                       (((x >> 3) & 1) << 4) | (((x >> 9) & 1) << 5); }

typedef __attribute__((ext_vector_type(2))) float v2;

// ---------------- cross-lane exchange helpers ----------------
template<int C>
__device__ __forceinline__ int dpp1(int x) {
  return __builtin_amdgcn_update_dpp(x, x, C, 0xF, 0xF, false);
}
template<int VL>
__device__ __forceinline__ int lxi(int x) {   // DPP xor-exchange, 1 <= VL <= 15
  if constexpr (VL == 1)  return dpp1<0xB1>(x);
  else if constexpr (VL == 2)  return dpp1<0x4E>(x);
  else if constexpr (VL == 3)  return dpp1<0x1B>(x);
  else if constexpr (VL <= 7) {
    constexpr int q = (VL & 3) ^ 3;
    int y = x;
    if constexpr (q == 1) y = dpp1<0xB1>(y);
    else if constexpr (q == 2) y = dpp1<0x4E>(y);
    else if constexpr (q == 3) y = dpp1<0x1B>(y);
    return dpp1<0x141>(y);                      // ^7
  } else if constexpr (VL >= 12) {
    constexpr int q = (VL & 3) ^ 3;
    int y = x;
    if constexpr (q == 1) y = dpp1<0xB1>(y);
    else if constexpr (q == 2) y = dpp1<0x4E>(y);
    else if constexpr (q == 3) y = dpp1<0x1B>(y);
    return dpp1<0x140>(y);                      // ^15
  } else {
    constexpr int a = VL & 3;
    int y = x;
    if constexpr (a == 1) y = dpp1<0xB1>(y);
    else if constexpr (a == 2) y = dpp1<0x4E>(y);
    else if constexpr (a == 3) y = dpp1<0x1B>(y);
    y = dpp1<0x141>(y);
    return dpp1<0x140>(y);
  }
}
template<int VL>
__device__ __forceinline__ float lx(float x) {
  if constexpr (VL == 0) return x;
  else if constexpr (VL & 32) {
    int addr = ((int)threadIdx.x ^ VL) << 2;
    return __int_as_float(__builtin_amdgcn_ds_bpermute(addr, __float_as_int(x)));
  } else if constexpr (VL & 16) {
    return __int_as_float(__builtin_amdgcn_ds_swizzle(__float_as_int(x), (VL << 10) | 0x1F));
  } else {
    return __int_as_float(lxi<VL>(__float_as_int(x)));
  }
}
__device__ __forceinline__ float rdl(float x, int l) {
  return __int_as_float(__builtin_amdgcn_readlane(__float_as_int(x), l));
}
__device__ __forceinline__ v2 cswap(v2 a) { return __builtin_shufflevector(a, a, 1, 0); }

// ---------------- fused gate pair ----------------
template<int PI>
__device__ __forceinline__ void gate_pair(v2* amp, int lane, const float4 (*kv)[4][2]) {
  constexpr int G1 = 2 * PI, G2 = 2 * PI + 1;
  constexpr int V1 = CT.vu[G1 / 10][G1 % 10], M1 = CT.mu[G1 / 10][G1 % 10];
  constexpr int V2 = CT.vu[G2 / 10][G2 % 10], M2 = CT.mu[G2 / 10][G2 % 10];
  constexpr int V3 = V1 ^ V2;
  constexpr int VL1 = lanePart(V1), VR1 = regPart(V1);
  constexpr int VL2 = lanePart(V2), VR2 = regPart(V2);
  constexpr int VL3 = lanePart(V3), VR3 = regPart(V3);
  constexpr int LM1 = lanePart(M1), LM2 = lanePart(M2);
  constexpr int RM1 = regPart(M1),  RM2 = regPart(M2);

  const int plw1 = __popc(lane & LM1) & 1;
  const int plw2 = __popc(lane & LM2) & 1;

  // variant sets: S[i][j] = coeffs valid for r with (pr1=i, pr2=j)
  float4 Sa[2][2], Sb[2][2];
#pragma unroll
  for (int i = 0; i < 2; ++i)
#pragma unroll
    for (int j = 0; j < 2; ++j) {
      const int v = ((plw1 ^ i) << 1) | (plw2 ^ j);
      Sa[i][j] = kv[PI][v][0];
      Sb[i][j] = kv[PI][v][1];
    }

  v2 p1[16], p2[16], p3[16];
#pragma unroll
  for (int r = 0; r < 16; ++r) { v2 s = amp[r ^ VR1]; p1[r].x = lx<VL1>(s.x); p1[r].y = lx<VL1>(s.y); }
#pragma unroll
  for (int r = 0; r < 16; ++r) { v2 s = amp[r ^ VR2]; p2[r].x = lx<VL2>(s.x); p2[r].y = lx<VL2>(s.y); }
#pragma unroll
  for (int r = 0; r < 16; ++r) { v2 s = amp[r ^ VR3]; p3[r].x = lx<VL3>(s.x); p3[r].y = lx<VL3>(s.y); }

#pragma unroll
  for (int r = 0; r < 16; ++r) {
    const int pr1 = __popc(r & RM1) & 1;     // compile-time after unroll
    const int pr2 = __popc(r & RM2) & 1;
    const float4 A = Sa[pr1][pr2], B = Sb[pr1][pr2];
    v2 a = amp[r];
    v2 res = A.x * a;
    res += v2{-A.y, A.y} * cswap(a);
    res += A.z * p1[r];
    res += v2{-A.w, A.w} * cswap(p1[r]);
    res += B.x * p2[r];
    res += v2{-B.y, B.y} * cswap(p2[r]);
    res += B.z * p3[r];
    res += v2{-B.w, B.w} * cswap(p3[r]);
    amp[r] = res;
  }
}

// ---------------- <X_w>: per-lane partial ----------------
template<int V>
__device__ __forceinline__ float xdot(const v2* amp) {
  constexpr int VL = lanePart(V), VR = regPart(V);
  v2 acc = {0.f, 0.f};
#pragma unroll
  for (int r = 0; r < 16; ++r) {
    v2 s = amp[r ^ VR];
    v2 p; p.x = lx<VL>(s.x); p.y = lx<VL>(s.y);
    acc += amp[r] * p;
  }
  return acc.x + acc.y;
}

// ---------------- main kernel: one wave per batch element ----------------
__global__ __launch_bounds__(NTHR, 1) void qmamba_main(
    const float* __restrict__ angles, const float* __restrict__ Wx,
    const float* __restrict__ Wdt, const float* __restrict__ bdt,
    const float* __restrict__ pc, const float* __restrict__ cp,
    float* __restrict__ out)
{
  __shared__ float  tblL[SEQ][RECF];   // 73728 B: th @0..9, cf @12..21, sf @24..33
  __shared__ float4 uuL[40];           // per-gate U (build only)
  __shared__ float4 kvL[10][4][2];     // fused pair coefficients: 1280 B

  const int lane = threadIdx.x;
  const int b    = blockIdx.x;

  // prologue 1: fused variational unitaries U = RZ(g)*RY(be)*RX(al)
  if (lane < 20) {
    int k = lane * 3;
    float al = 0.5f * cp[k], be = 0.5f * cp[k + 1], ga = 0.5f * cp[k + 2];
    float ca = __cosf(al), sa = __sinf(al);
    float cb = __cosf(be), sb = __sinf(be);
    float cg = __cosf(ga), sg = __sinf(ga);
    float2 M00 = make_float2(cb * ca,  sb * sa);
    float2 M01 = make_float2(-sb * ca, -cb * sa);
    float2 M10 = make_float2(sb * ca,  -cb * sa);
    float2 M11 = make_float2(cb * ca,  -sb * sa);
    float2 e0 = make_float2(cg, -sg), e1 = make_float2(cg, sg);
    auto cm = [](float2 a, float2 c) {
      return make_float2(a.x * c.x - a.y * c.y, a.x * c.y + a.y * c.x);
    };
    float2 u00 = cm(M00, e0), u01 = cm(M01, e0), u10 = cm(M10, e1), u11 = cm(M11, e1);
    uuL[2 * lane]     = make_float4(u00.x, u00.y, u01.x, u01.y);
    uuL[2 * lane + 1] = make_float4(u10.x, u10.y, u11.x, u11.y);
  }
  __syncthreads();

  // prologue 1b: fused pair coefficients (lane = pi*4 + (p<<1|q))
  if (lane < 40) {
    const int pi = lane >> 2, p = (lane >> 1) & 1, q = lane & 1;
    const int g1 = 2 * pi, g2 = 2 * pi + 1;
    float4 U1a = uuL[2 * g1], U1b = uuL[2 * g1 + 1];
    float4 U2a = uuL[2 * g2], U2b = uuL[2 * g2 + 1];
    float2 u1[2][2] = {{{U1a.x, U1a.y}, {U1a.z, U1a.w}}, {{U1b.x, U1b.y}, {U1b.z, U1b.w}}};
    float2 u2[2][2] = {{{U2a.x, U2a.y}, {U2a.z, U2a.w}}, {{U2b.x, U2b.y}, {U2b.z, U2b.w}}};
    // d[pi] via readlane-free constexpr table
    int d = CT.dp[pi];
    int pp = p ^ d;
    auto cm = [](float2 a, float2 c) {
      return make_float2(a.x * c.x - a.y * c.y, a.x * c.y + a.y * c.x);
    };
    float2 k00 = cm(u2[q][q],     u1[p][p]);
    float2 k01 = cm(u2[q][q],     u1[p][p ^ 1]);
    float2 k10 = cm(u2[q][q ^ 1], u1[pp][pp]);
    float2 k11 = cm(u2[q][q ^ 1], u1[pp][pp ^ 1]);
    kvL[pi][(p << 1) | q][0] = make_float4(k00.x, k00.y, k01.x, k01.y);
    kvL[pi][(p << 1) | q][1] = make_float4(k10.x, k10.y, k11.x, k11.y);
  }

  // prologue 2: per-step tables (each lane computes 8 steps)
#pragma unroll 1
  for (int k = 0; k < 8; ++k) {
    const int t = k * 64 + lane;
    const float* ar = angles + (size_t)(b * SEQ + t) * NQ;
    float a[NQ];
#pragma unroll
    for (int n = 0; n < NQ; ++n) a[n] = ar[n];
    float dtr[5];
#pragma unroll
    for (int r = 0; r < 5; ++r) {
      float acc = 0.f;
#pragma unroll
      for (int n = 0; n < NQ; ++n) acc += a[n] * Wx[r * NQ + n];
      dtr[r] = acc;
    }
    float* rec = &tblL[t][0];
#pragma unroll
    for (int w = 0; w < NQ; ++w) {
      float lin = bdt[w];
#pragma unroll
      for (int r = 0; r < 5; ++r) lin += dtr[r] * Wdt[w * 5 + r];
      float sp = lin > 0.f ? lin + log1pf(__expf(-lin)) : log1pf(__expf(lin));
      float th = tanhf(sp) * PIF;
      float fa = a[w] * th;
      rec[w]      = th;
      rec[12 + w] = __cosf(fa);
      rec[24 + w] = __sinf(fa);
    }
  }
  __syncthreads();

  float pch[4];
#pragma unroll
  for (int d = 0; d < 4; ++d) pch[d] = 0.5f * pc[d] * PIF;

  unsigned PW0 = 0, PW1 = 0;
#pragma unroll
  for (int k = 0; k < 40; ++k) {
    const int lm = lanePart(CT.mz[k / 10][k % 10]);
    unsigned flip = (__popc(lane & lm) & 1) ^ 1;
    if (k < 32) PW0 |= flip << k; else PW1 |= flip << (k - 32);
  }

  float hcw[NQ], hsw[NQ];
#pragma unroll
  for (int w = 0; w < NQ; ++w) { hcw[w] = 1.f; hsw[w] = 0.f; }

  v2 amp[16];

#pragma unroll 1
  for (int t = 0; t < SEQ; ++t) {
    // ---- th table (transient)
    float tha[12];
    {
      const float4* rq = (const float4*)&tblL[t][0];
#pragma unroll
      for (int j = 0; j < 3; ++j) ((float4*)tha)[j] = rq[j];
    }

    // ---- Phase A: real product state from RY(h)|0>
    float F;
    F  = (lane & 1)  ? hsw[9] : hcw[9];
    F *= (lane & 2)  ? hsw[4] : hcw[4];
    F *= (lane & 4)  ? hsw[8] : hcw[8];
    F *= (lane & 8)  ? hsw[2] : hcw[2];
    F *= (lane & 16) ? hsw[6] : hcw[6];
    F *= (lane & 32) ? hsw[0] : hcw[0];
    float G[16];
    {
      float g01[4], g23[4];
      g01[0] = hcw[7] * hcw[5]; g01[1] = hsw[7] * hcw[5];
      g01[2] = hcw[7] * hsw[5]; g01[3] = hsw[7] * hsw[5];
      g23[0] = hcw[3] * hcw[1]; g23[1] = hsw[3] * hcw[1];
      g23[2] = hcw[3] * hsw[1]; g23[3] = hsw[3] * hsw[1];
#pragma unroll
      for (int r = 0; r < 16; ++r) G[r] = F * g01[r & 3] * g23[(r >> 2) & 3];
    }

    // ---- Phase B: fused 40-RZ phase
    float S[16];
#pragma unroll
    for (int g = 0; g < 16; ++g) S[g] = 0.f;
#pragma unroll
    for (int k = 0; k < 40; ++k) {
      const int m  = CT.mz[k / 10][k % 10];
      const int gr = regPart(m);
      float v = pch[k / 10] * tha[k % 10];
      unsigned fl = ((k < 32 ? (PW0 >> k) : (PW1 >> (k - 32))) & 1u) << 31;
      S[gr] += __int_as_float(__float_as_int(v) ^ fl);
    }
#pragma unroll
    for (int bb = 1; bb < 16; bb <<= 1) {
#pragma unroll
      for (int g = 0; g < 16; ++g)
        if (!(g & bb)) { float x = S[g], y = S[g | bb]; S[g] = x + y; S[g | bb] = x - y; }
    }
#pragma unroll
    for (int r = 0; r < 16; ++r) {
      float sn, cs;
      __sincosf(S[r], &sn, &cs);
      amp[r].x = G[r] * cs;
      amp[r].y = G[r] * sn;
    }

    // ---- Phase C: 10 fused gate-pair rounds
    gate_pair<0>(amp, lane, kvL);
    gate_pair<1>(amp, lane, kvL);
    gate_pair<2>(amp, lane, kvL);
    gate_pair<3>(amp, lane, kvL);
    gate_pair<4>(amp, lane, kvL);
    gate_pair<5>(amp, lane, kvL);
    gate_pair<6>(amp, lane, kvL);
    gate_pair<7>(amp, lane, kvL);
    gate_pair<8>(amp, lane, kvL);
    gate_pair<9>(amp, lane, kvL);

    // ---- cf/sf tables (transient)
    float cfv[12], sfv[12];
    {
      const float4* rq = (const float4*)&tblL[t][0];
#pragma unroll
      for (int j = 0; j < 3; ++j) { ((float4*)cfv)[j] = rq[3 + j]; ((float4*)sfv)[j] = rq[6 + j]; }
    }

    // ---- measurement with fused final-RY: z_w = cos*<Z_w> - sin*<X_w>
    float T[16];
#pragma unroll
    for (int r = 0; r < 16; ++r) T[r] = amp[r].x * amp[r].x + amp[r].y * amp[r].y;
#pragma unroll
    for (int bb = 1; bb < 16; bb <<= 1) {
#pragma unroll
      for (int g = 0; g < 16; ++g)
        if (!(g & bb)) { float x = T[g], y = T[g | bb]; T[g] = x + y; T[g | bb] = x - y; }
    }
    float zv[NQ];
#define MEAS(W) {                                                   \
      constexpr int zmv = CT.zm[W];                                 \
      float zp = T[regPart(zmv)];                                   \
      if (__popc(lane & lanePart(zmv)) & 1) zp = -zp;               \
      float xp = xdot<CT.vf[W]>(amp);                               \
      zv[W] = cfv[W] * zp - sfv[W] * xp;                            \
    }
    MEAS(0) MEAS(1) MEAS(2) MEAS(3) MEAS(4)
    MEAS(5) MEAS(6) MEAS(7) MEAS(8) MEAS(9)
#undef MEAS

    // 3 shared DPP stages, pack by lane&7, 3 more stages -> lane w holds z_w
#pragma unroll
    for (int w = 0; w < NQ; ++w) {
      zv[w] += lx<1>(zv[w]);
      zv[w] += lx<2>(zv[w]);
      zv[w] += lx<4>(zv[w]);
    }
    const int l7 = lane & 7;
    float c01 = (l7 & 1) ? zv[1] : zv[0];
    float c23 = (l7 & 1) ? zv[3] : zv[2];
    float c45 = (l7 & 1) ? zv[5] : zv[4];
    float c67 = (l7 & 1) ? zv[7] : zv[6];
    float c03 = (l7 & 2) ? c23 : c01;
    float c47 = (l7 & 2) ? c67 : c45;
    float pk  = (l7 & 4) ? c47 : c03;
    pk += lx<8>(pk);  pk += lx<16>(pk);  pk += lx<32>(pk);
    float z8 = zv[8]; z8 += lx<8>(z8); z8 += lx<16>(z8); z8 += lx<32>(z8);
    float z9 = zv[9]; z9 += lx<8>(z9); z9 += lx<16>(z9); z9 += lx<32>(z9);
    float zsel = pk;
    zsel = (lane == 8) ? z8 : zsel;
    zsel = (lane == 9) ? z9 : zsel;

    // raw z store (fire-and-forget; post-kernel applies C*z + D*a)
    if (lane < NQ) out[(size_t)(b * SEQ + t) * NQ + lane] = zsel;

    // h for next step: lane w's sincos, broadcast via readlane
    float sn_h, cs_h;
    __sincosf(0.5f * zsel, &sn_h, &cs_h);
#pragma unroll
    for (int w = 0; w < NQ; ++w) { hcw[w] = rdl(cs_h, w); hsw[w] = rdl(sn_h, w); }
  }
}

// ---------------- post kernel: out = C*z + D*a, in place ----------------
__global__ __launch_bounds__(256) void qmamba_post(
    const float* __restrict__ angles, const float* __restrict__ Wx,
    const float* __restrict__ Dg, float* __restrict__ out)
{
  int i = blockIdx.x * 256 + threadIdx.x;          // 0 .. 128*512*10-1
  if (i >= NB * SEQ * NQ) return;
  int w  = i % NQ;
  int bt = i / NQ;
  const float* a = angles + (size_t)bt * NQ;
  float C = 0.f;
#pragma unroll
  for (int n = 0; n < NQ; ++n) C += a[n] * Wx[(15 + w) * NQ + n];
  float z = out[i];
  out[i] = C * z + Dg[w] * a[w];
}

extern "C" void kernel_launch(void* const* d_in, const int* in_sizes, int n_in,
                              void* d_out, int out_size, void* d_ws, size_t ws_size,
                              hipStream_t stream) {
  (void)in_sizes; (void)n_in; (void)out_size; (void)d_ws; (void)ws_size;
  const float* angles = (const float*)d_in[0];
  const float* Wx     = (const float*)d_in[1];
  const float* Wdt    = (const float*)d_in[2];
  const float* bdt    = (const float*)d_in[3];
  const float* pc     = (const float*)d_in[4];
  const float* cp     = (const float*)d_in[5];
  const float* Dg     = (const float*)d_in[6];
  float* out = (float*)d_out;
  hipLaunchKernelGGL(qmamba_main, dim3(NB), dim3(NTHR), 0, stream,
                     angles, Wx, Wdt, bdt, pc, cp, out);
  hipLaunchKernelGGL(qmamba_post, dim3((NB * SEQ * NQ + 255) / 256), dim3(256), 0, stream,
                     angles, Wx, Dg, out);
}

// Round 9
// 6716.538 us; speedup vs baseline: 1.0103x; 1.0103x over previous
//
#include <hip/hip_runtime.h>
#include <math.h>

// QuantumMambaSSMCore R9: R7 + rolled generic Phase-C gate loop (I-cache fix).
//  - 1 wave/block, 128 blocks, 16 amps/thread (v2 = complex).
//  - Storage map: regs r0..r3 = phys {2,4,6,8}; lanes L0..L5 = phys {0,5,1,7,3,9}.
//  - Phase C: ONE runtime loop over 20 gates. Snapshot amps to 8 KB LDS
//    (r-major), partner = 16 ds_read_b64 at XOR offset (same-wave DS ops are
//    in-order -> no barrier). SU(2) structure (u11=u00*, u10=-u01*) reduces
//    each gate to one float4 coeff + a per-(lane,r) sign folded into 10 FMAs.
//    Static body ~20 KB (was ~70 KB unrolled) -> fits 32 KB L1I.
//  - Tables {th, cos, sin} in 74 KB LDS; raw z stored; post-kernel C*z+D*a.

#define PIF 3.14159265358979323846f

constexpr int NQ = 10, SEQ = 512, NB = 128, NTHR = 64, RECF = 36;

struct CTbl { int vu[2][NQ], mu[2][NQ], mz[4][NQ], vf[NQ], zm[NQ]; };

constexpr CTbl build_tbl() {
  CTbl t{};
  unsigned mrow[NQ], vcol[NQ];
  for (int b = 0; b < NQ; ++b) { mrow[b] = 1u << b; vcol[b] = 1u << b; }
  for (int d = 0; d < 4; ++d) {
    for (int i = 0; i < NQ; ++i) t.mz[d][i] = (int)mrow[9 - i];
    for (int i = 0; i < NQ - 1; ++i) {           // CNOT(i, i+1)
      int bc = 9 - i, bt = 8 - i;
      mrow[bt] ^= mrow[bc];
      vcol[bc] ^= vcol[bt];
    }
    { int bc = 0, bt = 9;                        // CNOT(9, 0)
      mrow[bt] ^= mrow[bc];
      vcol[bc] ^= vcol[bt]; }
  }
  for (int l = 0; l < 2; ++l) {
    for (int i = 0; i < NQ; ++i) { t.vu[l][i] = (int)vcol[9 - i]; t.mu[l][i] = (int)mrow[9 - i]; }
    for (int i = 0; i < NQ - 1; ++i) {
      int bc = 9 - i, bt = 8 - i;
      mrow[bt] ^= mrow[bc];
      vcol[bc] ^= vcol[bt];
    }
  }
  for (int i = 0; i < NQ; ++i) t.vf[i] = (int)vcol[9 - i];
  for (int i = 0; i < NQ; ++i) t.zm[i] = (int)mrow[9 - i];
  return t;
}
constexpr CTbl CT = build_tbl();

constexpr int regPart(int x)  { return ((x >> 2) & 1) | (((x >> 4) & 1) << 1) |
                                       (((x >> 6) & 1) << 2) | (((x >> 8) & 1) << 3); }
constexpr int lanePart(int x) { return ((x >> 0) & 1) | (((x >> 5) & 1) << 1) |
                                       (((x >> 1) & 1) << 2) | (((x >> 7) & 1) << 3) |
                                       (((x >> 3) & 1) << 4) | (((x >> 9) & 1) << 5); }

// runtime gate descriptors (indexed by rolled loop counter -> .rodata s_load)
struct GDesc { int xr[20], xl[20], lm[20]; unsigned prm[20]; };
constexpr GDesc build_gd() {
  GDesc g{};
  for (int i = 0; i < 20; ++i) {
    int V = CT.vu[i / 10][i % 10], M = CT.mu[i / 10][i % 10];
    g.xr[i] = regPart(V) * 512;     // byte XOR offset in r dimension (row = 512B)
    g.xl[i] = lanePart(V) * 8;      // byte XOR offset in lane dimension (8B elems)
    g.lm[i] = lanePart(M);
    unsigned pm = 0;
    for (int r = 0; r < 16; ++r) {
      int x = r & regPart(M), c = 0;
      for (int b2 = 0; b2 < 4; ++b2) c ^= (x >> b2) & 1;
      pm |= (unsigned)c << r;
    }
    g.prm[i] = pm;
  }
  return g;
}
constexpr GDesc GD = build_gd();

typedef __attribute__((ext_vector_type(2))) float v2;

// ---------------- cross-lane exchange helpers (for xdot / reductions) -------
template<int C>
__device__ __forceinline__ int dpp1(int x) {
  return __builtin_amdgcn_update_dpp(x, x, C, 0xF, 0xF, false);
}
template<int VL>
__device__ __forceinline__ int lxi(int x) {   // DPP xor-exchange, 1 <= VL <= 15
  if constexpr (VL == 1)  return dpp1<0xB1>(x);
  else if constexpr (VL == 2)  return dpp1<0x4E>(x);
  else if constexpr (VL == 3)  return dpp1<0x1B>(x);
  else if constexpr (VL <= 7) {
    constexpr int q = (VL & 3) ^ 3;
    int y = x;
    if constexpr (q == 1) y = dpp1<0xB1>(y);
    else if constexpr (q == 2) y = dpp1<0x4E>(y);
    else if constexpr (q == 3) y = dpp1<0x1B>(y);
    return dpp1<0x141>(y);                      // ^7
  } else if constexpr (VL >= 12) {
    constexpr int q = (VL & 3) ^ 3;
    int y = x;
    if constexpr (q == 1) y = dpp1<0xB1>(y);
    else if constexpr (q == 2) y = dpp1<0x4E>(y);
    else if constexpr (q == 3) y = dpp1<0x1B>(y);
    return dpp1<0x140>(y);                      // ^15
  } else {
    constexpr int a = VL & 3;
    int y = x;
    if constexpr (a == 1) y = dpp1<0xB1>(y);
    else if constexpr (a == 2) y = dpp1<0x4E>(y);
    else if constexpr (a == 3) y = dpp1<0x1B>(y);
    y = dpp1<0x141>(y);
    return dpp1<0x140>(y);
  }
}
template<int VL>
__device__ __forceinline__ float lx(float x) {
  if constexpr (VL == 0) return x;
  else if constexpr (VL & 32) {
    int addr = ((int)threadIdx.x ^ VL) << 2;
    return __int_as_float(__builtin_amdgcn_ds_bpermute(addr, __float_as_int(x)));
  } else if constexpr (VL & 16) {
    return __int_as_float(__builtin_amdgcn_ds_swizzle(__float_as_int(x), (VL << 10) | 0x1F));
  } else {
    return __int_as_float(lxi<VL>(__float_as_int(x)));
  }
}
__device__ __forceinline__ float rdl(float x, int l) {
  return __int_as_float(__builtin_amdgcn_readlane(__float_as_int(x), l));
}

// ---------------- <X_w>: per-lane partial ----------------
template<int V>
__device__ __forceinline__ float xdot(const v2* amp) {
  constexpr int VL = lanePart(V), VR = regPart(V);
  v2 acc = {0.f, 0.f};
#pragma unroll
  for (int r = 0; r < 16; ++r) {
    v2 s = amp[r ^ VR];
    v2 p; p.x = lx<VL>(s.x); p.y = lx<VL>(s.y);
    acc += amp[r] * p;
  }
  return acc.x + acc.y;
}

// ---------------- main kernel: one wave per batch element ----------------
__global__ __launch_bounds__(NTHR, 1) void qmamba_main(
    const float* __restrict__ angles, const float* __restrict__ Wx,
    const float* __restrict__ Wdt, const float* __restrict__ bdt,
    const float* __restrict__ pc, const float* __restrict__ cp,
    float* __restrict__ out)
{
  __shared__ float  tblL[SEQ][RECF];   // 73728 B: th @0..9, cf @12..21, sf @24..33
  __shared__ v2     stateL[16][64];    // 8192 B r-major amp snapshot
  __shared__ float4 uuL4[20];          // fused U: (u00.x,u00.y,u01.x,u01.y)

  const int lane = threadIdx.x;
  const int b    = blockIdx.x;

  // prologue 1: fused variational unitaries U = RZ(g)*RY(be)*RX(al) (SU(2))
  if (lane < 20) {
    int k = lane * 3;
    float al = 0.5f * cp[k], be = 0.5f * cp[k + 1], ga = 0.5f * cp[k + 2];
    float ca = __cosf(al), sa = __sinf(al);
    float cb = __cosf(be), sb = __sinf(be);
    float cg = __cosf(ga), sg = __sinf(ga);
    float2 M00 = make_float2(cb * ca,  sb * sa);
    float2 M01 = make_float2(-sb * ca, -cb * sa);
    float2 e0 = make_float2(cg, -sg);
    auto cm = [](float2 a, float2 c) {
      return make_float2(a.x * c.x - a.y * c.y, a.x * c.y + a.y * c.x);
    };
    float2 u00 = cm(M00, e0), u01 = cm(M01, e0);
    uuL4[lane] = make_float4(u00.x, u00.y, u01.x, u01.y);
  }

  // prologue 2: per-step tables (each lane computes 8 steps)
#pragma unroll 1
  for (int k = 0; k < 8; ++k) {
    const int t = k * 64 + lane;
    const float* ar = angles + (size_t)(b * SEQ + t) * NQ;
    float a[NQ];
#pragma unroll
    for (int n = 0; n < NQ; ++n) a[n] = ar[n];
    float dtr[5];
#pragma unroll
    for (int r = 0; r < 5; ++r) {
      float acc = 0.f;
#pragma unroll
      for (int n = 0; n < NQ; ++n) acc += a[n] * Wx[r * NQ + n];
      dtr[r] = acc;
    }
    float* rec = &tblL[t][0];
#pragma unroll
    for (int w = 0; w < NQ; ++w) {
      float lin = bdt[w];
#pragma unroll
      for (int r = 0; r < 5; ++r) lin += dtr[r] * Wdt[w * 5 + r];
      float sp = lin > 0.f ? lin + log1pf(__expf(-lin)) : log1pf(__expf(lin));
      float th = tanhf(sp) * PIF;
      float fa = a[w] * th;
      rec[w]      = th;
      rec[12 + w] = __cosf(fa);
      rec[24 + w] = __sinf(fa);
    }
  }
  __syncthreads();   // single wave: one-time

  float pch[4];
#pragma unroll
  for (int d = 0; d < 4; ++d) pch[d] = 0.5f * pc[d] * PIF;

  unsigned PW0 = 0, PW1 = 0;
#pragma unroll
  for (int k = 0; k < 40; ++k) {
    const int lm = lanePart(CT.mz[k / 10][k % 10]);
    unsigned flip = (__popc(lane & lm) & 1) ^ 1;
    if (k < 32) PW0 |= flip << k; else PW1 |= flip << (k - 32);
  }

  float hcw[NQ], hsw[NQ];
#pragma unroll
  for (int w = 0; w < NQ; ++w) { hcw[w] = 1.f; hsw[w] = 0.f; }

  v2 amp[16];
  char* sbase = (char*)&stateL[0][0];

#pragma unroll 1
  for (int t = 0; t < SEQ; ++t) {
    // ---- th table (transient)
    float tha[12];
    {
      const float4* rq = (const float4*)&tblL[t][0];
#pragma unroll
      for (int j = 0; j < 3; ++j) ((float4*)tha)[j] = rq[j];
    }

    // ---- Phase A: real product state from RY(h)|0>
    float F;
    F  = (lane & 1)  ? hsw[9] : hcw[9];
    F *= (lane & 2)  ? hsw[4] : hcw[4];
    F *= (lane & 4)  ? hsw[8] : hcw[8];
    F *= (lane & 8)  ? hsw[2] : hcw[2];
    F *= (lane & 16) ? hsw[6] : hcw[6];
    F *= (lane & 32) ? hsw[0] : hcw[0];
    float G[16];
    {
      float g01[4], g23[4];
      g01[0] = hcw[7] * hcw[5]; g01[1] = hsw[7] * hcw[5];
      g01[2] = hcw[7] * hsw[5]; g01[3] = hsw[7] * hsw[5];
      g23[0] = hcw[3] * hcw[1]; g23[1] = hsw[3] * hcw[1];
      g23[2] = hcw[3] * hsw[1]; g23[3] = hsw[3] * hsw[1];
#pragma unroll
      for (int r = 0; r < 16; ++r) G[r] = F * g01[r & 3] * g23[(r >> 2) & 3];
    }

    // ---- Phase B: fused 40-RZ phase
    float S[16];
#pragma unroll
    for (int g = 0; g < 16; ++g) S[g] = 0.f;
#pragma unroll
    for (int k = 0; k < 40; ++k) {
      const int m  = CT.mz[k / 10][k % 10];
      const int gr = regPart(m);
      float v = pch[k / 10] * tha[k % 10];
      unsigned fl = ((k < 32 ? (PW0 >> k) : (PW1 >> (k - 32))) & 1u) << 31;
      S[gr] += __int_as_float(__float_as_int(v) ^ fl);
    }
#pragma unroll
    for (int bb = 1; bb < 16; bb <<= 1) {
#pragma unroll
      for (int g = 0; g < 16; ++g)
        if (!(g & bb)) { float x = S[g], y = S[g | bb]; S[g] = x + y; S[g | bb] = x - y; }
    }
#pragma unroll
    for (int r = 0; r < 16; ++r) {
      float sn, cs;
      __sincosf(S[r], &sn, &cs);
      amp[r].x = G[r] * cs;
      amp[r].y = G[r] * sn;
    }

    // ---- Phase C: 20 gates, rolled generic loop (compact I-footprint).
    // out(s) = u00*a(s) + u01*a(s^V)            for parity(s&M)=0
    //        = conj(u00)*a(s) - conj(u01)*a(s^V) for parity=1
    // = with s=+-1: re/im mix with ONE sign -> 10 FMA per amp.
#pragma unroll 1
    for (int g = 0; g < 20; ++g) {
      const float4 U = uuL4[g];
      const int lm = GD.lm[g];
      const unsigned prm = GD.prm[g];
      const int xr = GD.xr[g], xl = GD.xl[g];
      const float plw = (__popc(lane & lm) & 1) ? -1.f : 1.f;
      // snapshot own 16 amps (r-major: addr = r*512 + lane*8)
#pragma unroll
      for (int r = 0; r < 16; ++r)
        *(v2*)(sbase + r * 512 + lane * 8) = amp[r];
      const int ro = (lane * 8) ^ xl;
      // stream partner reads + in-place update (same-wave DS ops in order)
#pragma unroll
      for (int r = 0; r < 16; ++r) {
        v2 q = *(const v2*)(sbase + (((r * 512) ^ xr) + ro));
        float srf = __int_as_float(__float_as_int(plw) ^
                     ((prm << (31 - r)) & 0x80000000u));
        v2 o = amp[r];
        float ix = fmaf(U.z, q.x, -U.y * o.y);
        float iy = fmaf(U.z, q.y,  U.y * o.x);
        float rx = fmaf(U.x, o.x, -U.w * q.y);
        float ry = fmaf(U.x, o.y,  U.w * q.x);
        amp[r].x = fmaf(srf, ix, rx);
        amp[r].y = fmaf(srf, iy, ry);
      }
    }

    // ---- cf/sf tables (transient)
    float cfv[12], sfv[12];
    {
      const float4* rq = (const float4*)&tblL[t][0];
#pragma unroll
      for (int j = 0; j < 3; ++j) { ((float4*)cfv)[j] = rq[3 + j]; ((float4*)sfv)[j] = rq[6 + j]; }
    }

    // ---- measurement with fused final-RY: z_w = cos*<Z_w> - sin*<X_w>
    float T[16];
#pragma unroll
    for (int r = 0; r < 16; ++r) T[r] = amp[r].x * amp[r].x + amp[r].y * amp[r].y;
#pragma unroll
    for (int bb = 1; bb < 16; bb <<= 1) {
#pragma unroll
      for (int g = 0; g < 16; ++g)
        if (!(g & bb)) { float x = T[g], y = T[g | bb]; T[g] = x + y; T[g | bb] = x - y; }
    }
    float zv[NQ];
#define MEAS(W) {                                                   \
      constexpr int zmv = CT.zm[W];                                 \
      float zp = T[regPart(zmv)];                                   \
      if (__popc(lane & lanePart(zmv)) & 1) zp = -zp;               \
      float xp = xdot<CT.vf[W]>(amp);                               \
      zv[W] = cfv[W] * zp - sfv[W] * xp;                            \
    }
    MEAS(0) MEAS(1) MEAS(2) MEAS(3) MEAS(4)
    MEAS(5) MEAS(6) MEAS(7) MEAS(8) MEAS(9)
#undef MEAS

    // 3 shared DPP stages, pack by lane&7, 3 more stages -> lane w holds z_w
#pragma unroll
    for (int w = 0; w < NQ; ++w) {
      zv[w] += lx<1>(zv[w]);
      zv[w] += lx<2>(zv[w]);
      zv[w] += lx<4>(zv[w]);
    }
    const int l7 = lane & 7;
    float c01 = (l7 & 1) ? zv[1] : zv[0];
    float c23 = (l7 & 1) ? zv[3] : zv[2];
    float c45 = (l7 & 1) ? zv[5] : zv[4];
    float c67 = (l7 & 1) ? zv[7] : zv[6];
    float c03 = (l7 & 2) ? c23 : c01;
    float c47 = (l7 & 2) ? c67 : c45;
    float pk  = (l7 & 4) ? c47 : c03;
    pk += lx<8>(pk);  pk += lx<16>(pk);  pk += lx<32>(pk);
    float z8 = zv[8]; z8 += lx<8>(z8); z8 += lx<16>(z8); z8 += lx<32>(z8);
    float z9 = zv[9]; z9 += lx<8>(z9); z9 += lx<16>(z9); z9 += lx<32>(z9);
    float zsel = pk;
    zsel = (lane == 8) ? z8 : zsel;
    zsel = (lane == 9) ? z9 : zsel;

    // raw z store (fire-and-forget; post-kernel applies C*z + D*a)
    if (lane < NQ) out[(size_t)(b * SEQ + t) * NQ + lane] = zsel;

    // h for next step: lane w's sincos, broadcast via readlane
    float sn_h, cs_h;
    __sincosf(0.5f * zsel, &sn_h, &cs_h);
#pragma unroll
    for (int w = 0; w < NQ; ++w) { hcw[w] = rdl(cs_h, w); hsw[w] = rdl(sn_h, w); }
  }
}

// ---------------- post kernel: out = C*z + D*a, in place ----------------
__global__ __launch_bounds__(256) void qmamba_post(
    const float* __restrict__ angles, const float* __restrict__ Wx,
    const float* __restrict__ Dg, float* __restrict__ out)
{
  int i = blockIdx.x * 256 + threadIdx.x;          // 0 .. 128*512*10-1
  if (i >= NB * SEQ * NQ) return;
  int w  = i % NQ;
  int bt = i / NQ;
  const float* a = angles + (size_t)bt * NQ;
  float C = 0.f;
#pragma unroll
  for (int n = 0; n < NQ; ++n) C += a[n] * Wx[(15 + w) * NQ + n];
  float z = out[i];
  out[i] = C * z + Dg[w] * a[w];
}

extern "C" void kernel_launch(void* const* d_in, const int* in_sizes, int n_in,
                              void* d_out, int out_size, void* d_ws, size_t ws_size,
                              hipStream_t stream) {
  (void)in_sizes; (void)n_in; (void)out_size; (void)d_ws; (void)ws_size;
  const float* angles = (const float*)d_in[0];
  const float* Wx     = (const float*)d_in[1];
  const float* Wdt    = (const float*)d_in[2];
  const float* bdt    = (const float*)d_in[3];
  const float* pc     = (const float*)d_in[4];
  const float* cp     = (const float*)d_in[5];
  const float* Dg     = (const float*)d_in[6];
  float* out = (float*)d_out;
  hipLaunchKernelGGL(qmamba_main, dim3(NB), dim3(NTHR), 0, stream,
                     angles, Wx, Wdt, bdt, pc, cp, out);
  hipLaunchKernelGGL(qmamba_post, dim3((NB * SEQ * NQ + 255) / 256), dim3(256), 0, stream,
                     angles, Wx, Dg, out);
}

// Round 10
// 5171.659 us; speedup vs baseline: 1.3121x; 1.2987x over previous
//
#include <hip/hip_runtime.h>
#include <math.h>

// QuantumMambaSSMCore R10: R7 + optimal GF(2) storage basis.
//  - 1 wave/block, 128 blocks, 16 amps/thread (v2 = complex).
//  - Storage map chosen so regs = span of layer-0 gates 6..9 (in the folded
//    basis) and lane bits = layer-0 gates 0..5. Result (constexpr-derived from
//    the real CT tables): Phase C = 8 register-local / 7 DPP / 2 swizzle /
//    3 bpermute gates (R7: 2/10/3/5); xdot = 4 free / 2 DPP / 2 swz / 2 bperm.
//  - All masks/offsets transformed via constexpr Gauss elimination (B^T / B^-1).
//  - Phase A generalized: phys bit = parity of slot bits (per-r product form).
//  - Tables {th, cos, sin} in 74 KB LDS; raw z stored; post-kernel C*z+D*a.

#define PIF 3.14159265358979323846f

constexpr int NQ = 10, SEQ = 512, NB = 128, NTHR = 64, RECF = 36;

struct CTbl { int vu[2][NQ], mu[2][NQ], mz[4][NQ], vf[NQ], zm[NQ]; };

constexpr CTbl build_tbl() {
  CTbl t{};
  unsigned mrow[NQ], vcol[NQ];
  for (int b = 0; b < NQ; ++b) { mrow[b] = 1u << b; vcol[b] = 1u << b; }
  for (int d = 0; d < 4; ++d) {
    for (int i = 0; i < NQ; ++i) t.mz[d][i] = (int)mrow[9 - i];
    for (int i = 0; i < NQ - 1; ++i) {           // CNOT(i, i+1)
      int bc = 9 - i, bt = 8 - i;
      mrow[bt] ^= mrow[bc];
      vcol[bc] ^= vcol[bt];
    }
    { int bc = 0, bt = 9;                        // CNOT(9, 0)
      mrow[bt] ^= mrow[bc];
      vcol[bc] ^= vcol[bt]; }
  }
  for (int l = 0; l < 2; ++l) {
    for (int i = 0; i < NQ; ++i) { t.vu[l][i] = (int)vcol[9 - i]; t.mu[l][i] = (int)mrow[9 - i]; }
    for (int i = 0; i < NQ - 1; ++i) {
      int bc = 9 - i, bt = 8 - i;
      mrow[bt] ^= mrow[bc];
      vcol[bc] ^= vcol[bt];
    }
  }
  for (int i = 0; i < NQ; ++i) t.vf[i] = (int)vcol[9 - i];
  for (int i = 0; i < NQ; ++i) t.zm[i] = (int)mrow[9 - i];
  return t;
}
constexpr CTbl CT = build_tbl();

// ---- storage basis: slot->phys columns. regs r0..r3 = L0 gates 6..9;
//      lane bits L0..L5 = L0 gates 0..5 (these 10 vectors form a basis).
constexpr int basis_col(int k) {
  return (k < 4) ? CT.vu[0][6 + k] : CT.vu[0][k - 4];
}
constexpr int par10(int x) { int c = 0; for (int b = 0; b < 10; ++b) c ^= (x >> b) & 1; return c; }
// slot-row mask for phys bit p: bits k where basis_col(k) has bit p
constexpr int browOf(int p) {
  int m = 0;
  for (int k = 0; k < 10; ++k) m |= ((basis_col(k) >> p) & 1) << k;
  return m;
}
// parity-mask transform: M_slot = B^T M  (bit k = parity(col_k & M))
constexpr int maskToSlot(int M) {
  int m = 0;
  for (int k = 0; k < 10; ++k) m |= par10(basis_col(k) & M) << k;
  return m;
}
// XOR-offset transform: solve B x = V (row Gauss-Jordan over F2)
constexpr int physToSlot(int V) {
  unsigned row[10] = {};
  for (int b = 0; b < 10; ++b) {
    unsigned r = 0;
    for (int k = 0; k < 10; ++k) r |= (unsigned)((basis_col(k) >> b) & 1) << k;
    r |= (unsigned)((V >> b) & 1) << 10;
    row[b] = r;
  }
  bool used[10] = {};
  for (int k = 0; k < 10; ++k) {
    int pr = -1;
    for (int b = 0; b < 10; ++b) if (!used[b] && ((row[b] >> k) & 1)) { pr = b; break; }
    used[pr] = true;                    // pr==-1 would fail constexpr eval (basis check)
    for (int b = 0; b < 10; ++b) if (b != pr && ((row[b] >> k) & 1)) row[b] ^= row[pr];
  }
  int x = 0;
  for (int b = 0; b < 10; ++b) {
    unsigned c = row[b] & 0x3FFu;
    int k = 0;
    while (!((c >> k) & 1)) ++k;
    x |= (int)((row[b] >> 10) & 1) << k;
  }
  return x;
}

struct SMap { int brow[10]; int vS[20]; int mS[20]; int mzS[40]; int vfS[10]; int zmS[10]; };
constexpr SMap build_sm() {
  SMap s{};
  for (int p = 0; p < 10; ++p) s.brow[p] = browOf(p);
  for (int g = 0; g < 20; ++g) {
    s.vS[g] = physToSlot(CT.vu[g / 10][g % 10]);
    s.mS[g] = maskToSlot(CT.mu[g / 10][g % 10]);
  }
  for (int k = 0; k < 40; ++k) s.mzS[k] = maskToSlot(CT.mz[k / 10][k % 10]);
  for (int w = 0; w < 10; ++w) {
    s.vfS[w] = physToSlot(CT.vf[w]);
    s.zmS[w] = maskToSlot(CT.zm[w]);
  }
  return s;
}
constexpr SMap SM = build_sm();

typedef __attribute__((ext_vector_type(2))) float v2;

// ---------------- cross-lane exchange helpers ----------------
template<int C>
__device__ __forceinline__ int dpp1(int x) {
  return __builtin_amdgcn_update_dpp(x, x, C, 0xF, 0xF, false);
}
template<int VL>
__device__ __forceinline__ int lxi(int x) {   // DPP xor-exchange, 1 <= VL <= 15
  if constexpr (VL == 1)  return dpp1<0xB1>(x);
  else if constexpr (VL == 2)  return dpp1<0x4E>(x);
  else if constexpr (VL == 3)  return dpp1<0x1B>(x);
  else if constexpr (VL <= 7) {
    constexpr int q = (VL & 3) ^ 3;
    int y = x;
    if constexpr (q == 1) y = dpp1<0xB1>(y);
    else if constexpr (q == 2) y = dpp1<0x4E>(y);
    else if constexpr (q == 3) y = dpp1<0x1B>(y);
    return dpp1<0x141>(y);                      // ^7
  } else if constexpr (VL >= 12) {
    constexpr int q = (VL & 3) ^ 3;
    int y = x;
    if constexpr (q == 1) y = dpp1<0xB1>(y);
    else if constexpr (q == 2) y = dpp1<0x4E>(y);
    else if constexpr (q == 3) y = dpp1<0x1B>(y);
    return dpp1<0x140>(y);                      // ^15
  } else {
    constexpr int a = VL & 3;
    int y = x;
    if constexpr (a == 1) y = dpp1<0xB1>(y);
    else if constexpr (a == 2) y = dpp1<0x4E>(y);
    else if constexpr (a == 3) y = dpp1<0x1B>(y);
    y = dpp1<0x141>(y);
    return dpp1<0x140>(y);
  }
}
template<int VL>
__device__ __forceinline__ float lx(float x) {
  if constexpr (VL == 0) return x;
  else if constexpr (VL & 32) {
    int addr = ((int)threadIdx.x ^ VL) << 2;
    return __int_as_float(__builtin_amdgcn_ds_bpermute(addr, __float_as_int(x)));
  } else if constexpr (VL & 16) {
    return __int_as_float(__builtin_amdgcn_ds_swizzle(__float_as_int(x), (VL << 10) | 0x1F));
  } else {
    return __int_as_float(lxi<VL>(__float_as_int(x)));
  }
}
__device__ __forceinline__ float rdl(float x, int l) {
  return __int_as_float(__builtin_amdgcn_readlane(__float_as_int(x), l));
}

// ---------------- gate: fused constant SU(2), slot-space params ----------------
template<int SV, int SMK>
__device__ __forceinline__ void gate_u(v2* amp, float4 U0, float4 U1, int lane) {
  constexpr int VL = SV >> 4, VR = SV & 15;
  constexpr int LM = SMK >> 4, RM = SMK & 15;
  v2 p[16];
#pragma unroll
  for (int r = 0; r < 16; ++r) {
    v2 s = amp[r ^ VR];
    p[r].x = lx<VL>(s.x);
    p[r].y = lx<VL>(s.y);
  }
  const bool plw = (__popc(lane & LM) & 1) != 0;
  v2 u00 = {U0.x, U0.y}, u01 = {U0.z, U0.w}, u10 = {U1.x, U1.y}, u11 = {U1.z, U1.w};
  v2 A0 = plw ? u11 : u00, B0 = plw ? u10 : u01;
  v2 A1 = plw ? u00 : u11, B1 = plw ? u01 : u10;
  v2 A0n = {-A0.y, A0.y}, B0n = {-B0.y, B0.y};
  v2 A1n = {-A1.y, A1.y}, B1n = {-B1.y, B1.y};
#pragma unroll
  for (int r = 0; r < 16; ++r) {
    const bool pr = (__popc(r & RM) & 1) != 0;
    v2 A = pr ? A1 : A0, An = pr ? A1n : A0n;
    v2 B = pr ? B1 : B0, Bn = pr ? B1n : B0n;
    v2 o = amp[r], q = p[r];
    v2 res = A.x * o;
    res += An * __builtin_shufflevector(o, o, 1, 0);
    res += B.x * q;
    res += Bn * __builtin_shufflevector(q, q, 1, 0);
    amp[r] = res;
  }
}

// ---------------- <X_w>: per-lane partial (slot-space offset) ----------------
template<int SV>
__device__ __forceinline__ float xdot(const v2* amp) {
  constexpr int VL = SV >> 4, VR = SV & 15;
  v2 acc = {0.f, 0.f};
#pragma unroll
  for (int r = 0; r < 16; ++r) {
    v2 s = amp[r ^ VR];
    v2 p; p.x = lx<VL>(s.x); p.y = lx<VL>(s.y);
    acc += amp[r] * p;
  }
  return acc.x + acc.y;
}

// ---------------- main kernel: one wave per batch element ----------------
__global__ __launch_bounds__(NTHR, 1) void qmamba_main(
    const float* __restrict__ angles, const float* __restrict__ Wx,
    const float* __restrict__ Wdt, const float* __restrict__ bdt,
    const float* __restrict__ pc, const float* __restrict__ cp,
    float* __restrict__ out)
{
  __shared__ float  tblL[SEQ][RECF];   // 73728 B: th @0..9, cf @12..21, sf @24..33
  __shared__ float4 uuL[40];           // 640 B

  const int lane = threadIdx.x;
  const int b    = blockIdx.x;

  // prologue 1: fused variational unitaries U = RZ(g)*RY(be)*RX(al)
  if (lane < 20) {
    int k = lane * 3;
    float al = 0.5f * cp[k], be = 0.5f * cp[k + 1], ga = 0.5f * cp[k + 2];
    float ca = __cosf(al), sa = __sinf(al);
    float cb = __cosf(be), sb = __sinf(be);
    float cg = __cosf(ga), sg = __sinf(ga);
    float2 M00 = make_float2(cb * ca,  sb * sa);
    float2 M01 = make_float2(-sb * ca, -cb * sa);
    float2 M10 = make_float2(sb * ca,  -cb * sa);
    float2 M11 = make_float2(cb * ca,  -sb * sa);
    float2 e0 = make_float2(cg, -sg), e1 = make_float2(cg, sg);
    auto cm = [](float2 a, float2 c) {
      return make_float2(a.x * c.x - a.y * c.y, a.x * c.y + a.y * c.x);
    };
    float2 u00 = cm(M00, e0), u01 = cm(M01, e0), u10 = cm(M10, e1), u11 = cm(M11, e1);
    uuL[2 * lane]     = make_float4(u00.x, u00.y, u01.x, u01.y);
    uuL[2 * lane + 1] = make_float4(u10.x, u10.y, u11.x, u11.y);
  }

  // prologue 2: per-step tables (each lane computes 8 steps)
#pragma unroll 1
  for (int k = 0; k < 8; ++k) {
    const int t = k * 64 + lane;
    const float* ar = angles + (size_t)(b * SEQ + t) * NQ;
    float a[NQ];
#pragma unroll
    for (int n = 0; n < NQ; ++n) a[n] = ar[n];
    float dtr[5];
#pragma unroll
    for (int r = 0; r < 5; ++r) {
      float acc = 0.f;
#pragma unroll
      for (int n = 0; n < NQ; ++n) acc += a[n] * Wx[r * NQ + n];
      dtr[r] = acc;
    }
    float* rec = &tblL[t][0];
#pragma unroll
    for (int w = 0; w < NQ; ++w) {
      float lin = bdt[w];
#pragma unroll
      for (int r = 0; r < 5; ++r) lin += dtr[r] * Wdt[w * 5 + r];
      float sp = lin > 0.f ? lin + log1pf(__expf(-lin)) : log1pf(__expf(lin));
      float th = tanhf(sp) * PIF;
      float fa = a[w] * th;
      rec[w]      = th;
      rec[12 + w] = __cosf(fa);
      rec[24 + w] = __sinf(fa);
    }
  }
  __syncthreads();   // single wave: one-time

  float pch[4];
#pragma unroll
  for (int d = 0; d < 4; ++d) pch[d] = 0.5f * pc[d] * PIF;

  // hoisted lane-parity bits for the 40 fused-RZ slot masks
  unsigned PW0 = 0, PW1 = 0;
#pragma unroll
  for (int k = 0; k < 40; ++k) {
    const int lm = SM.mzS[k] >> 4;
    unsigned flip = (__popc(lane & lm) & 1) ^ 1;
    if (k < 32) PW0 |= flip << k; else PW1 |= flip << (k - 32);
  }

  // hoisted Phase-A lane parities: phys bit p = parity(r & brow&15) ^ plp[p]
  int plp[10];
#pragma unroll
  for (int p = 0; p < 10; ++p) plp[p] = __popc(lane & (SM.brow[p] >> 4)) & 1;

  float hcw[NQ], hsw[NQ];
#pragma unroll
  for (int w = 0; w < NQ; ++w) { hcw[w] = 1.f; hsw[w] = 0.f; }

  v2 amp[16];

#pragma unroll 1
  for (int t = 0; t < SEQ; ++t) {
    // ---- th table (transient)
    float tha[12];
    {
      const float4* rq = (const float4*)&tblL[t][0];
#pragma unroll
      for (int j = 0; j < 3; ++j) ((float4*)tha)[j] = rq[j];
    }

    // ---- Phase A: real product state from RY(h)|0> (generalized basis)
    float e0a[10], e1a[10];
#pragma unroll
    for (int p = 0; p < 10; ++p) {
      const int w = 9 - p;
      float c = hcw[w], s = hsw[w];
      e0a[p] = plp[p] ? s : c;    // factor when parity(r & rmask_p) == 0
      e1a[p] = plp[p] ? c : s;    // factor when parity == 1
    }
    float G[16];
#pragma unroll
    for (int r = 0; r < 16; ++r) {
      float g = 1.f;
#pragma unroll
      for (int p = 0; p < 10; ++p) {
        const int rm = SM.brow[p] & 15;          // compile-time after unroll
        g *= (__popc(r & rm) & 1) ? e1a[p] : e0a[p];
      }
      G[r] = g;
    }

    // ---- Phase B: fused 40-RZ phase (slot masks)
    float S[16];
#pragma unroll
    for (int g = 0; g < 16; ++g) S[g] = 0.f;
#pragma unroll
    for (int k = 0; k < 40; ++k) {
      const int gr = SM.mzS[k] & 15;
      float v = pch[k / 10] * tha[k % 10];
      unsigned fl = ((k < 32 ? (PW0 >> k) : (PW1 >> (k - 32))) & 1u) << 31;
      S[gr] += __int_as_float(__float_as_int(v) ^ fl);
    }
#pragma unroll
    for (int bb = 1; bb < 16; bb <<= 1) {
#pragma unroll
      for (int g = 0; g < 16; ++g)
        if (!(g & bb)) { float x = S[g], y = S[g | bb]; S[g] = x + y; S[g | bb] = x - y; }
    }
#pragma unroll
    for (int r = 0; r < 16; ++r) {
      float sn, cs;
      __sincosf(S[r], &sn, &cs);
      amp[r].x = G[r] * cs;
      amp[r].y = G[r] * sn;
    }

    // ---- Phase C: 20 fused SU(2) gates (8 register-local under new basis)
#define GU(G_) gate_u<SM.vS[G_], SM.mS[G_]>(amp, uuL[2*(G_)], uuL[2*(G_)+1], lane);
    GU(0)  GU(1)  GU(2)  GU(3)  GU(4)
    GU(5)  GU(6)  GU(7)  GU(8)  GU(9)
    GU(10) GU(11) GU(12) GU(13) GU(14)
    GU(15) GU(16) GU(17) GU(18) GU(19)
#undef GU

    // ---- cf/sf tables (transient)
    float cfv[12], sfv[12];
    {
      const float4* rq = (const float4*)&tblL[t][0];
#pragma unroll
      for (int j = 0; j < 3; ++j) { ((float4*)cfv)[j] = rq[3 + j]; ((float4*)sfv)[j] = rq[6 + j]; }
    }

    // ---- measurement with fused final-RY: z_w = cos*<Z_w> - sin*<X_w>
    float T[16];
#pragma unroll
    for (int r = 0; r < 16; ++r) T[r] = amp[r].x * amp[r].x + amp[r].y * amp[r].y;
#pragma unroll
    for (int bb = 1; bb < 16; bb <<= 1) {
#pragma unroll
      for (int g = 0; g < 16; ++g)
        if (!(g & bb)) { float x = T[g], y = T[g | bb]; T[g] = x + y; T[g | bb] = x - y; }
    }
    float zv[NQ];
#define MEAS(W) {                                                   \
      constexpr int zmv = SM.zmS[W];                                \
      float zp = T[zmv & 15];                                       \
      if (__popc(lane & (zmv >> 4)) & 1) zp = -zp;                  \
      float xp = xdot<SM.vfS[W]>(amp);                              \
      zv[W] = cfv[W] * zp - sfv[W] * xp;                            \
    }
    MEAS(0) MEAS(1) MEAS(2) MEAS(3) MEAS(4)
    MEAS(5) MEAS(6) MEAS(7) MEAS(8) MEAS(9)
#undef MEAS

    // 3 shared DPP stages, pack by lane&7, 3 more stages -> lane w holds z_w
#pragma unroll
    for (int w = 0; w < NQ; ++w) {
      zv[w] += lx<1>(zv[w]);
      zv[w] += lx<2>(zv[w]);
      zv[w] += lx<4>(zv[w]);
    }
    const int l7 = lane & 7;
    float c01 = (l7 & 1) ? zv[1] : zv[0];
    float c23 = (l7 & 1) ? zv[3] : zv[2];
    float c45 = (l7 & 1) ? zv[5] : zv[4];
    float c67 = (l7 & 1) ? zv[7] : zv[6];
    float c03 = (l7 & 2) ? c23 : c01;
    float c47 = (l7 & 2) ? c67 : c45;
    float pk  = (l7 & 4) ? c47 : c03;
    pk += lx<8>(pk);  pk += lx<16>(pk);  pk += lx<32>(pk);
    float z8 = zv[8]; z8 += lx<8>(z8); z8 += lx<16>(z8); z8 += lx<32>(z8);
    float z9 = zv[9]; z9 += lx<8>(z9); z9 += lx<16>(z9); z9 += lx<32>(z9);
    float zsel = pk;
    zsel = (lane == 8) ? z8 : zsel;
    zsel = (lane == 9) ? z9 : zsel;

    // raw z store (fire-and-forget; post-kernel applies C*z + D*a)
    if (lane < NQ) out[(size_t)(b * SEQ + t) * NQ + lane] = zsel;

    // h for next step: lane w's sincos, broadcast via readlane
    float sn_h, cs_h;
    __sincosf(0.5f * zsel, &sn_h, &cs_h);
#pragma unroll
    for (int w = 0; w < NQ; ++w) { hcw[w] = rdl(cs_h, w); hsw[w] = rdl(sn_h, w); }
  }
}

// ---------------- post kernel: out = C*z + D*a, in place ----------------
__global__ __launch_bounds__(256) void qmamba_post(
    const float* __restrict__ angles, const float* __restrict__ Wx,
    const float* __restrict__ Dg, float* __restrict__ out)
{
  int i = blockIdx.x * 256 + threadIdx.x;          // 0 .. 128*512*10-1
  if (i >= NB * SEQ * NQ) return;
  int w  = i % NQ;
  int bt = i / NQ;
  const float* a = angles + (size_t)bt * NQ;
  float C = 0.f;
#pragma unroll
  for (int n = 0; n < NQ; ++n) C += a[n] * Wx[(15 + w) * NQ + n];
  float z = out[i];
  out[i] = C * z + Dg[w] * a[w];
}

extern "C" void kernel_launch(void* const* d_in, const int* in_sizes, int n_in,
                              void* d_out, int out_size, void* d_ws, size_t ws_size,
                              hipStream_t stream) {
  (void)in_sizes; (void)n_in; (void)out_size; (void)d_ws; (void)ws_size;
  const float* angles = (const float*)d_in[0];
  const float* Wx     = (const float*)d_in[1];
  const float* Wdt    = (const float*)d_in[2];
  const float* bdt    = (const float*)d_in[3];
  const float* pc     = (const float*)d_in[4];
  const float* cp     = (const float*)d_in[5];
  const float* Dg     = (const float*)d_in[6];
  float* out = (float*)d_out;
  hipLaunchKernelGGL(qmamba_main, dim3(NB), dim3(NTHR), 0, stream,
                     angles, Wx, Wdt, bdt, pc, cp, out);
  hipLaunchKernelGGL(qmamba_post, dim3((NB * SEQ * NQ + 255) / 256), dim3(256), 0, stream,
                     angles, Wx, Dg, out);
}

// Round 11
// 5098.214 us; speedup vs baseline: 1.3310x; 1.0144x over previous
//
#include <hip/hip_runtime.h>
#include <math.h>

// QuantumMambaSSMCore R11: R7 engine, 2 independent waves per block (I-fetch
// amortization test). Each wave simulates its own batch element with the exact
// R7 single-wave algorithm; waves share the CU's L1I stream (identical code)
// but nothing else. 64 blocks x 128 threads; LDS = 2 x 73.7 KB private tables.
//  - Per-wave: 16 amps/thread; regs r0..r3 = phys {2,4,6,8}; lanes L0..L5 =
//    phys {0,5,1,7,3,9}. Zero barriers / zero global ops in the 512-step loop.
//  - Raw z stored fire-and-forget; C*z + D*a applied by parallel post-kernel.

#define PIF 3.14159265358979323846f

constexpr int NQ = 10, SEQ = 512, NB = 128, NBLK = 64, NTHR = 128, RECF = 36;

struct CTbl { int vu[2][NQ], mu[2][NQ], mz[4][NQ], vf[NQ], zm[NQ]; };

constexpr CTbl build_tbl() {
  CTbl t{};
  unsigned mrow[NQ], vcol[NQ];
  for (int b = 0; b < NQ; ++b) { mrow[b] = 1u << b; vcol[b] = 1u << b; }
  for (int d = 0; d < 4; ++d) {
    for (int i = 0; i < NQ; ++i) t.mz[d][i] = (int)mrow[9 - i];
    for (int i = 0; i < NQ - 1; ++i) {           // CNOT(i, i+1)
      int bc = 9 - i, bt = 8 - i;
      mrow[bt] ^= mrow[bc];
      vcol[bc] ^= vcol[bt];
    }
    { int bc = 0, bt = 9;                        // CNOT(9, 0)
      mrow[bt] ^= mrow[bc];
      vcol[bc] ^= vcol[bt]; }
  }
  for (int l = 0; l < 2; ++l) {
    for (int i = 0; i < NQ; ++i) { t.vu[l][i] = (int)vcol[9 - i]; t.mu[l][i] = (int)mrow[9 - i]; }
    for (int i = 0; i < NQ - 1; ++i) {
      int bc = 9 - i, bt = 8 - i;
      mrow[bt] ^= mrow[bc];
      vcol[bc] ^= vcol[bt];
    }
  }
  for (int i = 0; i < NQ; ++i) t.vf[i] = (int)vcol[9 - i];
  for (int i = 0; i < NQ; ++i) t.zm[i] = (int)mrow[9 - i];
  return t;
}
constexpr CTbl CT = build_tbl();

constexpr int regPart(int x)  { return ((x >> 2) & 1) | (((x >> 4) & 1) << 1) |
                                       (((x >> 6) & 1) << 2) | (((x >> 8) & 1) << 3); }
constexpr int lanePart(int x) { return ((x >> 0) & 1) | (((x >> 5) & 1) << 1) |
                                       (((x >> 1) & 1) << 2) | (((x >> 7) & 1) << 3) |
                                       (((x >> 3) & 1) << 4) | (((x >> 9) & 1) << 5); }

typedef __attribute__((ext_vector_type(2))) float v2;

// ---------------- cross-lane exchange helpers (wave-local) ----------------
template<int C>
__device__ __forceinline__ int dpp1(int x) {
  return __builtin_amdgcn_update_dpp(x, x, C, 0xF, 0xF, false);
}
template<int VL>
__device__ __forceinline__ int lxi(int x) {   // DPP xor-exchange, 1 <= VL <= 15
  if constexpr (VL == 1)  return dpp1<0xB1>(x);
  else if constexpr (VL == 2)  return dpp1<0x4E>(x);
  else if constexpr (VL == 3)  return dpp1<0x1B>(x);
  else if constexpr (VL <= 7) {
    constexpr int q = (VL & 3) ^ 3;
    int y = x;
    if constexpr (q == 1) y = dpp1<0xB1>(y);
    else if constexpr (q == 2) y = dpp1<0x4E>(y);
    else if constexpr (q == 3) y = dpp1<0x1B>(y);
    return dpp1<0x141>(y);                      // ^7
  } else if constexpr (VL >= 12) {
    constexpr int q = (VL & 3) ^ 3;
    int y = x;
    if constexpr (q == 1) y = dpp1<0xB1>(y);
    else if constexpr (q == 2) y = dpp1<0x4E>(y);
    else if constexpr (q == 3) y = dpp1<0x1B>(y);
    return dpp1<0x140>(y);                      // ^15
  } else {
    constexpr int a = VL & 3;
    int y = x;
    if constexpr (a == 1) y = dpp1<0xB1>(y);
    else if constexpr (a == 2) y = dpp1<0x4E>(y);
    else if constexpr (a == 3) y = dpp1<0x1B>(y);
    y = dpp1<0x141>(y);
    return dpp1<0x140>(y);
  }
}
template<int VL>
__device__ __forceinline__ float lx(float x) {
  if constexpr (VL == 0) return x;
  else if constexpr (VL & 32) {
    // bpermute lane index = (addr>>2) mod 64 within the executing wave
    int addr = ((int)threadIdx.x ^ VL) << 2;
    return __int_as_float(__builtin_amdgcn_ds_bpermute(addr, __float_as_int(x)));
  } else if constexpr (VL & 16) {
    return __int_as_float(__builtin_amdgcn_ds_swizzle(__float_as_int(x), (VL << 10) | 0x1F));
  } else {
    return __int_as_float(lxi<VL>(__float_as_int(x)));
  }
}
__device__ __forceinline__ float rdl(float x, int l) {
  return __int_as_float(__builtin_amdgcn_readlane(__float_as_int(x), l));
}

// ---------------- gate: fused constant SU(2), preloaded U ----------------
template<int V, int M>
__device__ __forceinline__ void gate_u(v2* amp, float4 U0, float4 U1, int lane) {
  constexpr int VL = lanePart(V), VR = regPart(V);
  constexpr int LM = lanePart(M), RM = regPart(M);
  v2 p[16];
#pragma unroll
  for (int r = 0; r < 16; ++r) {
    v2 s = amp[r ^ VR];
    p[r].x = lx<VL>(s.x);
    p[r].y = lx<VL>(s.y);
  }
  const bool plw = (__popc(lane & LM) & 1) != 0;
  v2 u00 = {U0.x, U0.y}, u01 = {U0.z, U0.w}, u10 = {U1.x, U1.y}, u11 = {U1.z, U1.w};
  v2 A0 = plw ? u11 : u00, B0 = plw ? u10 : u01;
  v2 A1 = plw ? u00 : u11, B1 = plw ? u01 : u10;
  v2 A0n = {-A0.y, A0.y}, B0n = {-B0.y, B0.y};
  v2 A1n = {-A1.y, A1.y}, B1n = {-B1.y, B1.y};
#pragma unroll
  for (int r = 0; r < 16; ++r) {
    const bool pr = (__popc(r & RM) & 1) != 0;
    v2 A = pr ? A1 : A0, An = pr ? A1n : A0n;
    v2 B = pr ? B1 : B0, Bn = pr ? B1n : B0n;
    v2 o = amp[r], q = p[r];
    v2 res = A.x * o;
    res += An * __builtin_shufflevector(o, o, 1, 0);
    res += B.x * q;
    res += Bn * __builtin_shufflevector(q, q, 1, 0);
    amp[r] = res;
  }
}

// ---------------- <X_w>: per-lane partial ----------------
template<int V>
__device__ __forceinline__ float xdot(const v2* amp) {
  constexpr int VL = lanePart(V), VR = regPart(V);
  v2 acc = {0.f, 0.f};
#pragma unroll
  for (int r = 0; r < 16; ++r) {
    v2 s = amp[r ^ VR];
    v2 p; p.x = lx<VL>(s.x); p.y = lx<VL>(s.y);
    acc += amp[r] * p;
  }
  return acc.x + acc.y;
}

// ---------------- main kernel: 2 independent waves per block ----------------
__global__ __launch_bounds__(NTHR, 1) void qmamba_main(
    const float* __restrict__ angles, const float* __restrict__ Wx,
    const float* __restrict__ Wdt, const float* __restrict__ bdt,
    const float* __restrict__ pc, const float* __restrict__ cp,
    float* __restrict__ out)
{
  __shared__ float  tblL[2][SEQ][RECF]; // 147456 B: th @0..9, cf @12..21, sf @24..33
  __shared__ float4 uuL[40];            // 640 B, shared by both waves

  const int tid  = threadIdx.x;
  const int lane = tid & 63;
  const int wid  = tid >> 6;
  const int b    = blockIdx.x * 2 + wid;     // each wave owns one batch element

  // prologue 1: fused variational unitaries U = RZ(g)*RY(be)*RX(al) (wave 0)
  if (tid < 20) {
    int k = tid * 3;
    float al = 0.5f * cp[k], be = 0.5f * cp[k + 1], ga = 0.5f * cp[k + 2];
    float ca = __cosf(al), sa = __sinf(al);
    float cb = __cosf(be), sb = __sinf(be);
    float cg = __cosf(ga), sg = __sinf(ga);
    float2 M00 = make_float2(cb * ca,  sb * sa);
    float2 M01 = make_float2(-sb * ca, -cb * sa);
    float2 M10 = make_float2(sb * ca,  -cb * sa);
    float2 M11 = make_float2(cb * ca,  -sb * sa);
    float2 e0 = make_float2(cg, -sg), e1 = make_float2(cg, sg);
    auto cm = [](float2 a, float2 c) {
      return make_float2(a.x * c.x - a.y * c.y, a.x * c.y + a.y * c.x);
    };
    float2 u00 = cm(M00, e0), u01 = cm(M01, e0), u10 = cm(M10, e1), u11 = cm(M11, e1);
    uuL[2 * tid]     = make_float4(u00.x, u00.y, u01.x, u01.y);
    uuL[2 * tid + 1] = make_float4(u10.x, u10.y, u11.x, u11.y);
  }

  // prologue 2: per-step tables (wave-private; each lane computes 8 steps)
#pragma unroll 1
  for (int k = 0; k < 8; ++k) {
    const int t = k * 64 + lane;
    const float* ar = angles + (size_t)(b * SEQ + t) * NQ;
    float a[NQ];
#pragma unroll
    for (int n = 0; n < NQ; ++n) a[n] = ar[n];
    float dtr[5];
#pragma unroll
    for (int r = 0; r < 5; ++r) {
      float acc = 0.f;
#pragma unroll
      for (int n = 0; n < NQ; ++n) acc += a[n] * Wx[r * NQ + n];
      dtr[r] = acc;
    }
    float* rec = &tblL[wid][t][0];
#pragma unroll
    for (int w = 0; w < NQ; ++w) {
      float lin = bdt[w];
#pragma unroll
      for (int r = 0; r < 5; ++r) lin += dtr[r] * Wdt[w * 5 + r];
      float sp = lin > 0.f ? lin + log1pf(__expf(-lin)) : log1pf(__expf(lin));
      float th = tanhf(sp) * PIF;
      float fa = a[w] * th;
      rec[w]      = th;
      rec[12 + w] = __cosf(fa);
      rec[24 + w] = __sinf(fa);
    }
  }
  __syncthreads();   // once: uuL visible to both waves; tables settled

  float pch[4];
#pragma unroll
  for (int d = 0; d < 4; ++d) pch[d] = 0.5f * pc[d] * PIF;

  // hoisted lane-parity bits for the 40 fused-RZ masks
  unsigned PW0 = 0, PW1 = 0;
#pragma unroll
  for (int k = 0; k < 40; ++k) {
    const int lm = lanePart(CT.mz[k / 10][k % 10]);
    unsigned flip = (__popc(lane & lm) & 1) ^ 1;
    if (k < 32) PW0 |= flip << k; else PW1 |= flip << (k - 32);
  }

  float hcw[NQ], hsw[NQ];
#pragma unroll
  for (int w = 0; w < NQ; ++w) { hcw[w] = 1.f; hsw[w] = 0.f; }

  v2 amp[16];

#pragma unroll 1
  for (int t = 0; t < SEQ; ++t) {
    // ---- th table (transient: dies at end of Phase B)
    float tha[12];
    {
      const float4* rq = (const float4*)&tblL[wid][t][0];
#pragma unroll
      for (int j = 0; j < 3; ++j) ((float4*)tha)[j] = rq[j];
    }

    // ---- Phase A: real product state from RY(h)|0>
    // lanes: L0=w9 L1=w4 L2=w8 L3=w2 L4=w6 L5=w0; regs: r0=w7 r1=w5 r2=w3 r3=w1
    float F;
    F  = (lane & 1)  ? hsw[9] : hcw[9];
    F *= (lane & 2)  ? hsw[4] : hcw[4];
    F *= (lane & 4)  ? hsw[8] : hcw[8];
    F *= (lane & 8)  ? hsw[2] : hcw[2];
    F *= (lane & 16) ? hsw[6] : hcw[6];
    F *= (lane & 32) ? hsw[0] : hcw[0];
    float G[16];
    {
      float g01[4], g23[4];
      g01[0] = hcw[7] * hcw[5]; g01[1] = hsw[7] * hcw[5];
      g01[2] = hcw[7] * hsw[5]; g01[3] = hsw[7] * hsw[5];
      g23[0] = hcw[3] * hcw[1]; g23[1] = hsw[3] * hcw[1];
      g23[2] = hcw[3] * hsw[1]; g23[3] = hsw[3] * hsw[1];
#pragma unroll
      for (int r = 0; r < 16; ++r) G[r] = F * g01[r & 3] * g23[(r >> 2) & 3];
    }

    // ---- Phase B: fused 40-RZ phase
    float S[16];
#pragma unroll
    for (int g = 0; g < 16; ++g) S[g] = 0.f;
#pragma unroll
    for (int k = 0; k < 40; ++k) {
      const int m  = CT.mz[k / 10][k % 10];
      const int gr = regPart(m);
      float v = pch[k / 10] * tha[k % 10];
      unsigned fl = ((k < 32 ? (PW0 >> k) : (PW1 >> (k - 32))) & 1u) << 31;
      S[gr] += __int_as_float(__float_as_int(v) ^ fl);
    }
#pragma unroll
    for (int bb = 1; bb < 16; bb <<= 1) {
#pragma unroll
      for (int g = 0; g < 16; ++g)
        if (!(g & bb)) { float x = S[g], y = S[g | bb]; S[g] = x + y; S[g | bb] = x - y; }
    }
#pragma unroll
    for (int r = 0; r < 16; ++r) {
      float sn, cs;
      __sincosf(S[r], &sn, &cs);
      amp[r].x = G[r] * cs;
      amp[r].y = G[r] * sn;
    }

    // ---- Phase C: 20 fused SU(2) gates
#define GU(L, I, G_) gate_u<CT.vu[L][I], CT.mu[L][I]>(amp, uuL[2*(G_)], uuL[2*(G_)+1], lane);
    GU(0, 0, 0)  GU(0, 1, 1)  GU(0, 2, 2)  GU(0, 3, 3)  GU(0, 4, 4)
    GU(0, 5, 5)  GU(0, 6, 6)  GU(0, 7, 7)  GU(0, 8, 8)  GU(0, 9, 9)
    GU(1, 0, 10) GU(1, 1, 11) GU(1, 2, 12) GU(1, 3, 13) GU(1, 4, 14)
    GU(1, 5, 15) GU(1, 6, 16) GU(1, 7, 17) GU(1, 8, 18) GU(1, 9, 19)
#undef GU

    // ---- cf/sf tables (transient)
    float cfv[12], sfv[12];
    {
      const float4* rq = (const float4*)&tblL[wid][t][0];
#pragma unroll
      for (int j = 0; j < 3; ++j) { ((float4*)cfv)[j] = rq[3 + j]; ((float4*)sfv)[j] = rq[6 + j]; }
    }

    // ---- measurement with fused final-RY: z_w = cos*<Z_w> - sin*<X_w>
    float T[16];
#pragma unroll
    for (int r = 0; r < 16; ++r) T[r] = amp[r].x * amp[r].x + amp[r].y * amp[r].y;
#pragma unroll
    for (int bb = 1; bb < 16; bb <<= 1) {
#pragma unroll
      for (int g = 0; g < 16; ++g)
        if (!(g & bb)) { float x = T[g], y = T[g | bb]; T[g] = x + y; T[g | bb] = x - y; }
    }
    float zv[NQ];
#define MEAS(W) {                                                   \
      constexpr int zmv = CT.zm[W];                                 \
      float zp = T[regPart(zmv)];                                   \
      if (__popc(lane & lanePart(zmv)) & 1) zp = -zp;               \
      float xp = xdot<CT.vf[W]>(amp);                               \
      zv[W] = cfv[W] * zp - sfv[W] * xp;                            \
    }
    MEAS(0) MEAS(1) MEAS(2) MEAS(3) MEAS(4)
    MEAS(5) MEAS(6) MEAS(7) MEAS(8) MEAS(9)
#undef MEAS

    // 3 shared DPP stages, pack by lane&7, 3 more stages -> lane w holds z_w
#pragma unroll
    for (int w = 0; w < NQ; ++w) {
      zv[w] += lx<1>(zv[w]);
      zv[w] += lx<2>(zv[w]);
      zv[w] += lx<4>(zv[w]);
    }
    const int l7 = lane & 7;
    float c01 = (l7 & 1) ? zv[1] : zv[0];
    float c23 = (l7 & 1) ? zv[3] : zv[2];
    float c45 = (l7 & 1) ? zv[5] : zv[4];
    float c67 = (l7 & 1) ? zv[7] : zv[6];
    float c03 = (l7 & 2) ? c23 : c01;
    float c47 = (l7 & 2) ? c67 : c45;
    float pk  = (l7 & 4) ? c47 : c03;
    pk += lx<8>(pk);  pk += lx<16>(pk);  pk += lx<32>(pk);
    float z8 = zv[8]; z8 += lx<8>(z8); z8 += lx<16>(z8); z8 += lx<32>(z8);
    float z9 = zv[9]; z9 += lx<8>(z9); z9 += lx<16>(z9); z9 += lx<32>(z9);
    float zsel = pk;
    zsel = (lane == 8) ? z8 : zsel;
    zsel = (lane == 9) ? z9 : zsel;

    // raw z store (fire-and-forget; post-kernel applies C*z + D*a)
    if (lane < NQ) out[(size_t)(b * SEQ + t) * NQ + lane] = zsel;

    // h for next step: lane w's sincos, broadcast via readlane
    float sn_h, cs_h;
    __sincosf(0.5f * zsel, &sn_h, &cs_h);
#pragma unroll
    for (int w = 0; w < NQ; ++w) { hcw[w] = rdl(cs_h, w); hsw[w] = rdl(sn_h, w); }
  }
}

// ---------------- post kernel: out = C*z + D*a, in place ----------------
__global__ __launch_bounds__(256) void qmamba_post(
    const float* __restrict__ angles, const float* __restrict__ Wx,
    const float* __restrict__ Dg, float* __restrict__ out)
{
  int i = blockIdx.x * 256 + threadIdx.x;          // 0 .. 128*512*10-1
  if (i >= NB * SEQ * NQ) return;
  int w  = i % NQ;
  int bt = i / NQ;
  const float* a = angles + (size_t)bt * NQ;
  float C = 0.f;
#pragma unroll
  for (int n = 0; n < NQ; ++n) C += a[n] * Wx[(15 + w) * NQ + n];
  float z = out[i];
  out[i] = C * z + Dg[w] * a[w];
}

extern "C" void kernel_launch(void* const* d_in, const int* in_sizes, int n_in,
                              void* d_out, int out_size, void* d_ws, size_t ws_size,
                              hipStream_t stream) {
  (void)in_sizes; (void)n_in; (void)out_size; (void)d_ws; (void)ws_size;
  const float* angles = (const float*)d_in[0];
  const float* Wx     = (const float*)d_in[1];
  const float* Wdt    = (const float*)d_in[2];
  const float* bdt    = (const float*)d_in[3];
  const float* pc     = (const float*)d_in[4];
  const float* cp     = (const float*)d_in[5];
  const float* Dg     = (const float*)d_in[6];
  float* out = (float*)d_out;
  hipLaunchKernelGGL(qmamba_main, dim3(NBLK), dim3(NTHR), 0, stream,
                     angles, Wx, Wdt, bdt, pc, cp, out);
  hipLaunchKernelGGL(qmamba_post, dim3((NB * SEQ * NQ + 255) / 256), dim3(256), 0, stream,
                     angles, Wx, Dg, out);
}